// Round 1
// baseline (2462.772 us; speedup 1.0000x reference)
//
#include <hip/hip_runtime.h>

// Problem constants (fixed by the reference)
#define GROUPS 64
#define DCOLS 256          // feature dim
#define NROWS (1 << 20)    // 1048576 rows
#define OUT_PER_G (3 * DCOLS)  // 768: [max || min || mean]

// Kernel tiling
#define COLS 64            // columns per block slice
#define SLICES (DCOLS / COLS)       // 4
#define ROWBLOCKS 128
#define ROWS_PER_BLOCK (NROWS / ROWBLOCKS)  // 8192
#define THREADS 1024
#define STREAMS (THREADS / 16)      // 64 rows in flight per block
#define ITERS (ROWS_PER_BLOCK / STREAMS)    // 128
#define LDS_STRIDE 65      // 64 + 1 pad: spreads groups across banks

// Monotone float -> uint key: unsigned compare == float compare (no NaNs in input)
__device__ __forceinline__ unsigned order_key(float x) {
    unsigned u = __float_as_uint(x);
    return u ^ (unsigned)(((int)u >> 31) | 0x80000000);
}
__device__ __forceinline__ float decode_key(unsigned k) {
    unsigned u = (k & 0x80000000u) ? (k ^ 0x80000000u) : ~k;
    return __uint_as_float(u);
}

// ---------------------------------------------------------------------------
// Init: out holds the accumulators in final layout [g][stat][c]:
//   stat 0 = max keys (init 0 = smallest key)
//   stat 1 = min keys (init 0xFFFFFFFF)
//   stat 2 = sum      (init 0.0f)
// ws[0..63] = counts (init 0)
__global__ void init_acc(unsigned* __restrict__ out_u, int* __restrict__ cnt) {
    int i = blockIdx.x * blockDim.x + threadIdx.x;  // grid covers 49152
    if (i < GROUPS * OUT_PER_G) {
        int stat = (i >> 8) % 3;  // i = g*768 + stat*256 + c
        unsigned v = (stat == 0) ? 0u : (stat == 1) ? 0xFFFFFFFFu : 0u;
        out_u[i] = v;
    }
    if (i < GROUPS) cnt[i] = 0;
}

// ---------------------------------------------------------------------------
// Main streaming pass: each block = (column slice s, row block rb).
// Threads: q = tid&15 owns a float4 (4 cols), st = tid>>4 is the row stream.
__global__ __launch_bounds__(THREADS, 8)
void seg_stats_kernel(const float* __restrict__ feat,
                      const int* __restrict__ gidx,
                      unsigned* __restrict__ out_u,
                      int* __restrict__ gcnt) {
    __shared__ unsigned sMax[GROUPS * LDS_STRIDE];
    __shared__ unsigned sMin[GROUPS * LDS_STRIDE];
    __shared__ float    sSum[GROUPS * LDS_STRIDE];
    __shared__ int      sCnt[GROUPS];

    const int tid = threadIdx.x;
    for (int i = tid; i < GROUPS * LDS_STRIDE; i += THREADS) {
        sMax[i] = 0u;
        sMin[i] = 0xFFFFFFFFu;
        sSum[i] = 0.0f;
    }
    if (tid < GROUPS) sCnt[tid] = 0;
    __syncthreads();

    const int s  = blockIdx.x & (SLICES - 1);
    const int rb = blockIdx.x >> 2;
    const int q  = tid & 15;   // column quad within slice
    const int st = tid >> 4;   // row stream
    const int row0 = rb * ROWS_PER_BLOCK + st;
    const bool do_count = (s == 0) && (q == 0);

    const float4* fp = (const float4*)(feat + (size_t)row0 * DCOLS + s * COLS) + q;
    const int* ip = gidx + row0;
    const size_t fstep = (size_t)STREAMS * (DCOLS / 4);  // float4 per iter

    float4 v = *fp;
    int g = *ip;
    for (int it = 0; it < ITERS; ++it) {
        float4 vn = v;
        int gn = g;
        if (it + 1 < ITERS) {
            vn = fp[(size_t)(it + 1) * fstep];
            gn = ip[(size_t)(it + 1) * STREAMS];
        }
        // swizzled LDS position: col c = q*4 + j stored at g*65 + j*16 + q
        // -> per-j ds op hits 16 consecutive banks per row cluster
        int base = g * LDS_STRIDE + q;
        {
            unsigned k = order_key(v.x);
            atomicMax(&sMax[base +  0], k);
            atomicMin(&sMin[base +  0], k);
            atomicAdd(&sSum[base +  0], v.x);
        }
        {
            unsigned k = order_key(v.y);
            atomicMax(&sMax[base + 16], k);
            atomicMin(&sMin[base + 16], k);
            atomicAdd(&sSum[base + 16], v.y);
        }
        {
            unsigned k = order_key(v.z);
            atomicMax(&sMax[base + 32], k);
            atomicMin(&sMin[base + 32], k);
            atomicAdd(&sSum[base + 32], v.z);
        }
        {
            unsigned k = order_key(v.w);
            atomicMax(&sMax[base + 48], k);
            atomicMin(&sMin[base + 48], k);
            atomicAdd(&sSum[base + 48], v.w);
        }
        if (do_count) atomicAdd(&sCnt[g], 1);
        v = vn;
        g = gn;
    }
    __syncthreads();

    // Merge block partials into global accumulators (in d_out).
    float* out_f = (float*)out_u;
    for (int i = tid; i < GROUPS * COLS; i += THREADS) {
        int g2 = i >> 6;
        int c  = i & 63;
        int pos = g2 * LDS_STRIDE + ((c & 3) << 4) + (c >> 2);  // de-swizzle
        int gi  = g2 * OUT_PER_G + s * COLS + c;                // stat-0 region
        atomicMax(&out_u[gi], sMax[pos]);
        atomicMin(&out_u[gi + DCOLS], sMin[pos]);
        atomicAdd(&out_f[gi + 2 * DCOLS], sSum[pos]);
    }
    if (do_count && tid < GROUPS * 16) {
        // only q==0 lanes reach here with do_count; tid<64 handles counts
    }
    if (s == 0 && tid < GROUPS) atomicAdd(&gcnt[tid], sCnt[tid]);
}

// ---------------------------------------------------------------------------
// Finalize in place: decode max/min keys, divide sum by count.
__global__ void finalize_kernel(unsigned* __restrict__ out_u,
                                const int* __restrict__ gcnt) {
    int g = blockIdx.x;
    int c = threadIdx.x;  // 256 threads
    float* out_f = (float*)out_u;
    int base = g * OUT_PER_G + c;

    unsigned kmax = out_u[base];
    unsigned kmin = out_u[base + DCOLS];
    float sum = out_f[base + 2 * DCOLS];
    float cnt = (float)gcnt[g];

    out_f[base]             = decode_key(kmax);
    out_f[base + DCOLS]     = decode_key(kmin);
    out_f[base + 2 * DCOLS] = sum / cnt;
}

// ---------------------------------------------------------------------------
extern "C" void kernel_launch(void* const* d_in, const int* in_sizes, int n_in,
                              void* d_out, int out_size, void* d_ws, size_t ws_size,
                              hipStream_t stream) {
    const float* feat = (const float*)d_in[0];
    const int* gidx = (const int*)d_in[1];
    unsigned* out_u = (unsigned*)d_out;
    int* gcnt = (int*)d_ws;  // 64 ints — only 256 B of ws needed

    // 1) init accumulators (49152 out words + 64 counts)
    init_acc<<<(GROUPS * OUT_PER_G + 255) / 256, 256, 0, stream>>>(out_u, gcnt);
    // 2) streaming pass: 512 blocks = 4 col slices x 128 row blocks
    seg_stats_kernel<<<SLICES * ROWBLOCKS, THREADS, 0, stream>>>(feat, gidx, out_u, gcnt);
    // 3) finalize in place
    finalize_kernel<<<GROUPS, DCOLS, 0, stream>>>(out_u, gcnt);
}